// Round 1
// 530.060 us; speedup vs baseline: 1.0359x; 1.0359x over previous
//
#include <hip/hip_runtime.h>
#include <hip/hip_bf16.h>

#define IN_F   4096
#define OUT_F  4096
#define HID    64
#define D_LAT  16
#define BLK    16
#define NB     (IN_F * OUT_F / BLK)   // 1,048,576
#define NCODES 65536                   // codebook size
#define M_TOT  8192                    // 4 * 2048
#define K_TOT  IN_F
#define N_TOT  OUT_F

typedef __bf16 bf16x8 __attribute__((ext_vector_type(8)));
typedef float  f32x4  __attribute__((ext_vector_type(4)));

// ---------------------------------------------------------------- convert x
__global__ __launch_bounds__(256) void convert_x_kernel(
    const float* __restrict__ x, __hip_bfloat16* __restrict__ xb) {
  size_t i = ((size_t)blockIdx.x * 256 + threadIdx.x) * 8;
  const float4* p = (const float4*)(x + i);
  float4 a = p[0], b = p[1];
  union { __hip_bfloat16 h[8]; uint4 q; } u;
  u.h[0] = __float2bfloat16(a.x); u.h[1] = __float2bfloat16(a.y);
  u.h[2] = __float2bfloat16(a.z); u.h[3] = __float2bfloat16(a.w);
  u.h[4] = __float2bfloat16(b.x); u.h[5] = __float2bfloat16(b.y);
  u.h[6] = __float2bfloat16(b.z); u.h[7] = __float2bfloat16(b.w);
  *(uint4*)(xb + i) = u.q;
}

// ---------------------------------------------------------------- decode TABLE (MFMA)
// Decode the 65,536 UNIQUE codebook entries once (not the 1M blocks):
// table[k][16] = relu(codebook[k]@W1 + b1)@W2 + b2   (fp32, no scale/shift).
// Same verified MFMA structure as before; per wave-step 16 sequential codes.
__global__ __launch_bounds__(256) void decode_table_kernel(
    const float* __restrict__ codebook,
    const float* __restrict__ W1, const float* __restrict__ b1,
    const float* __restrict__ W2, const float* __restrict__ b2,
    float* __restrict__ table) {
  __shared__ __align__(16) __hip_bfloat16 sH[4][16 * 72];  // per-wave h tile
  const int lane = threadIdx.x & 63;
  const int wave = threadIdx.x >> 6;
  const int n = lane & 15;   // col within 16
  const int q = lane >> 4;   // quad
  const bool act = q < 2;    // quads holding real K (k<16) for layer 1

  union { __hip_bfloat16 h[8]; bf16x8 v; } uz;
#pragma unroll
  for (int j = 0; j < 8; j++) uz.h[j] = __float2bfloat16(0.f);
  const bf16x8 zf = uz.v;
  const f32x4 z4 = (f32x4){0.f, 0.f, 0.f, 0.f};

  // B-frags layer1: frag1[g][j] = W1[k][g*16+n], k=q*8+j (zero for k>=16)
  bf16x8 frag1[4];
#pragma unroll
  for (int g = 0; g < 4; g++) {
    union { __hip_bfloat16 h[8]; bf16x8 v; } u;
#pragma unroll
    for (int j = 0; j < 8; j++) {
      int k = (q * 8 + j) & 15;
      float w = act ? W1[k * HID + g * 16 + n] : 0.f;
      u.h[j] = __float2bfloat16(w);
    }
    frag1[g] = u.v;
  }
  // B-frags layer2: frag2[kk][j] = W2[(kk*32+q*8+j)*16 + n]
  bf16x8 frag2[2];
#pragma unroll
  for (int kk = 0; kk < 2; kk++) {
    union { __hip_bfloat16 h[8]; bf16x8 v; } u;
#pragma unroll
    for (int j = 0; j < 8; j++)
      u.h[j] = __float2bfloat16(W2[(kk * 32 + q * 8 + j) * BLK + n]);
    frag2[kk] = u.v;
  }
  float b1v[4];
#pragma unroll
  for (int g = 0; g < 4; g++) b1v[g] = b1[g * 16 + n];
  const float b2v = b2[n];

  const int c0w = blockIdx.x * 256 + wave * 64;
#pragma unroll 1
  for (int i = 0; i < 4; i++) {
    const int cbase = c0w + i * 16;
    const int id = cbase + n;  // sequential: decoding the codebook itself
    const float4* cp = (const float4*)(codebook + (size_t)id * D_LAT + (q & 1) * 8);
    float4 ca = cp[0], cb = cp[1];
    union { __hip_bfloat16 h[8]; bf16x8 v; } ua;
    ua.h[0] = __float2bfloat16(ca.x); ua.h[1] = __float2bfloat16(ca.y);
    ua.h[2] = __float2bfloat16(ca.z); ua.h[3] = __float2bfloat16(ca.w);
    ua.h[4] = __float2bfloat16(cb.x); ua.h[5] = __float2bfloat16(cb.y);
    ua.h[6] = __float2bfloat16(cb.z); ua.h[7] = __float2bfloat16(cb.w);
    bf16x8 afrag = act ? ua.v : zf;

    f32x4 hC[4];
#pragma unroll
    for (int g = 0; g < 4; g++)
      hC[g] = __builtin_amdgcn_mfma_f32_16x16x32_bf16(afrag, frag1[g], z4, 0, 0, 0);

    __syncthreads();  // previous step's LDS reads complete
#pragma unroll
    for (int g = 0; g < 4; g++)
#pragma unroll
      for (int r = 0; r < 4; r++) {
        float hv = fmaxf(hC[g][r] + b1v[g], 0.f);
        sH[wave][(q * 4 + r) * 72 + g * 16 + n] = __float2bfloat16(hv);
      }
    __syncthreads();  // writes visible

    bf16x8 a2_0 = *(const bf16x8*)&sH[wave][n * 72 + q * 8];
    bf16x8 a2_1 = *(const bf16x8*)&sH[wave][n * 72 + 32 + q * 8];
    f32x4 o4 = __builtin_amdgcn_mfma_f32_16x16x32_bf16(a2_0, frag2[0], z4, 0, 0, 0);
    o4 = __builtin_amdgcn_mfma_f32_16x16x32_bf16(a2_1, frag2[1], o4, 0, 0, 0);

#pragma unroll
    for (int r = 0; r < 4; r++) {
      int code = cbase + q * 4 + r;
      table[(size_t)code * BLK + n] = o4[r] + b2v;  // fp32, pre-scale
    }
  }
}

// ---------------------------------------------------------------- gather + de-standardize
// What[b*16+j] = bf16(table[yidx[b]][j] * scale[b>>8] + shift[b>>8]).
// Each workgroup covers one output row o = blockIdx.x -> scale/shift are
// wave-uniform (scalar loads). Gather hits the L2-resident 4 MB table.
__global__ __launch_bounds__(256) void gather_scale_kernel(
    const int* __restrict__ yidx, const float* __restrict__ table,
    const float* __restrict__ scale, const float* __restrict__ shift,
    __hip_bfloat16* __restrict__ What) {
  const int b = blockIdx.x * 256 + threadIdx.x;   // weight-block index
  const int o = blockIdx.x;                        // = b >> 8 (256 blocks/row)
  const float sc = scale[o], sh = shift[o];
  const int id = yidx[b];
  const float4* t = (const float4*)(table + (size_t)id * BLK);
  float4 v0 = t[0], v1 = t[1], v2 = t[2], v3 = t[3];
  union { __hip_bfloat16 h[16]; uint4 q[2]; } u;
  u.h[0]  = __float2bfloat16(v0.x * sc + sh);
  u.h[1]  = __float2bfloat16(v0.y * sc + sh);
  u.h[2]  = __float2bfloat16(v0.z * sc + sh);
  u.h[3]  = __float2bfloat16(v0.w * sc + sh);
  u.h[4]  = __float2bfloat16(v1.x * sc + sh);
  u.h[5]  = __float2bfloat16(v1.y * sc + sh);
  u.h[6]  = __float2bfloat16(v1.z * sc + sh);
  u.h[7]  = __float2bfloat16(v1.w * sc + sh);
  u.h[8]  = __float2bfloat16(v2.x * sc + sh);
  u.h[9]  = __float2bfloat16(v2.y * sc + sh);
  u.h[10] = __float2bfloat16(v2.z * sc + sh);
  u.h[11] = __float2bfloat16(v2.w * sc + sh);
  u.h[12] = __float2bfloat16(v3.x * sc + sh);
  u.h[13] = __float2bfloat16(v3.y * sc + sh);
  u.h[14] = __float2bfloat16(v3.z * sc + sh);
  u.h[15] = __float2bfloat16(v3.w * sc + sh);
  uint4* dst = (uint4*)(What + (size_t)b * BLK);
  dst[0] = u.q[0];
  dst[1] = u.q[1];
}

// ---------------------------------------------------------------- GEMM
// C[m][n] = sum_k A[m][k] * B[n][k] + bias[n]   (B row-major [N][K])
// Block tile 256x128, BK=32. 4 waves in 2x2; wave tile 128x64 = 8x4 MFMAs.
// XOR chunk swizzle on the staging side kills LDS bank conflicts (R2: 0).
__device__ inline void gload_lds16(const void* g, void* l) {
  __builtin_amdgcn_global_load_lds(
      (const __attribute__((address_space(1))) void*)g,
      (__attribute__((address_space(3))) void*)l, 16, 0, 0);
}

__global__ __launch_bounds__(256, 2) void gemm_bt_kernel(
    const __hip_bfloat16* __restrict__ A, const __hip_bfloat16* __restrict__ B,
    const float* __restrict__ bias, float* __restrict__ C) {
  __shared__ __align__(16) __hip_bfloat16 sA[256 * 32];  // 16 KB
  __shared__ __align__(16) __hip_bfloat16 sB[128 * 32];  //  8 KB
  const int lane = threadIdx.x & 63;
  const int wave = threadIdx.x >> 6;
  const int m0 = blockIdx.y * 256;
  const int n0 = blockIdx.x * 128;
  const int wr = wave >> 1;
  const int wc = wave & 1;

  const int srow = lane >> 2;
  const int schk = (lane & 3) ^ ((lane >> 3) & 3);
  const __hip_bfloat16* aSrc =
      A + (size_t)(m0 + wave * 64 + srow) * K_TOT + schk * 8;
  const __hip_bfloat16* bSrc =
      B + (size_t)(n0 + wave * 32 + srow) * K_TOT + schk * 8;

  const int fl = lane & 15;
  const int pos = (lane >> 4) ^ ((fl >> 1) & 3);
  const __hip_bfloat16* aRd = &sA[(wr * 128 + fl) * 32 + pos * 8];
  const __hip_bfloat16* bRd = &sB[(wc * 64 + fl) * 32 + pos * 8];

  f32x4 acc[8][4];
#pragma unroll
  for (int i = 0; i < 8; i++)
#pragma unroll
    for (int j = 0; j < 4; j++) acc[i][j] = (f32x4){0.f, 0.f, 0.f, 0.f};

  for (int k0 = 0; k0 < K_TOT; k0 += 32) {
#pragma unroll
    for (int i = 0; i < 4; i++)
      gload_lds16(aSrc + (size_t)i * 16 * K_TOT + k0,
                  (char*)sA + (wave * 4 + i) * 1024);
#pragma unroll
    for (int i = 0; i < 2; i++)
      gload_lds16(bSrc + (size_t)i * 16 * K_TOT + k0,
                  (char*)sB + (wave * 2 + i) * 1024);
    __syncthreads();

    bf16x8 bf[4];
#pragma unroll
    for (int nt = 0; nt < 4; nt++) bf[nt] = *(const bf16x8*)(bRd + nt * 16 * 32);
#pragma unroll
    for (int mt = 0; mt < 8; mt++) {
      bf16x8 af = *(const bf16x8*)(aRd + mt * 16 * 32);
#pragma unroll
      for (int nt = 0; nt < 4; nt++)
        acc[mt][nt] = __builtin_amdgcn_mfma_f32_16x16x32_bf16(
            af, bf[nt], acc[mt][nt], 0, 0, 0);
    }
    __syncthreads();
  }

  float bs[4];
#pragma unroll
  for (int nt = 0; nt < 4; nt++) bs[nt] = bias[n0 + wc * 64 + nt * 16 + fl];
#pragma unroll
  for (int mt = 0; mt < 8; mt++) {
    int r0 = m0 + wr * 128 + mt * 16 + (lane >> 4) * 4;
#pragma unroll
    for (int nt = 0; nt < 4; nt++) {
      int cn = n0 + wc * 64 + nt * 16 + fl;
#pragma unroll
      for (int r = 0; r < 4; r++)
        C[(size_t)(r0 + r) * N_TOT + cn] = acc[mt][nt][r] + bs[nt];
    }
  }
}

// ---------------------------------------------------------------- launch
extern "C" void kernel_launch(void* const* d_in, const int* in_sizes, int n_in,
                              void* d_out, int out_size, void* d_ws, size_t ws_size,
                              hipStream_t stream) {
  const float* x        = (const float*)d_in[0];
  const int*   yidx     = (const int*)d_in[1];
  const float* codebook = (const float*)d_in[2];
  const float* W1       = (const float*)d_in[3];
  const float* b1       = (const float*)d_in[4];
  const float* W2       = (const float*)d_in[5];
  const float* b2       = (const float*)d_in[6];
  const float* scale    = (const float*)d_in[7];
  const float* shift    = (const float*)d_in[8];
  const float* bias     = (const float*)d_in[9];
  float* out = (float*)d_out;

  // Workspace layout (96 MB total):
  //   [0,32MB)  What  (bf16, 1M blocks x 16)
  //   [32,96MB) xb    (bf16 x)  -- its first 4 MB double as the fp32 decode
  //                               table, which is DEAD before convert_x runs
  //                               (stream-ordered: table -> gather -> convert).
  __hip_bfloat16* What = (__hip_bfloat16*)d_ws;                                     // 32 MB
  float* table = (float*)((char*)d_ws + (size_t)32 * 1024 * 1024);                  //  4 MB (aliased)
  __hip_bfloat16* xb   = (__hip_bfloat16*)((char*)d_ws + (size_t)32 * 1024 * 1024); // 64 MB

  decode_table_kernel<<<NCODES / 256, 256, 0, stream>>>(codebook, W1, b1, W2, b2,
                                                        table);
  gather_scale_kernel<<<NB / 256, 256, 0, stream>>>(yidx, table, scale, shift, What);
  convert_x_kernel<<<(M_TOT * (size_t)K_TOT) / (256 * 8), 256, 0, stream>>>(x, xb);
  gemm_bt_kernel<<<dim3(N_TOT / 128, M_TOT / 256), 256, 0, stream>>>(xb, What, bias, out);
}

// Round 3
// 484.340 us; speedup vs baseline: 1.1337x; 1.0944x over previous
//
#include <hip/hip_runtime.h>
#include <hip/hip_bf16.h>

#define IN_F   4096
#define OUT_F  4096
#define HID    64
#define D_LAT  16
#define BLK    16
#define NB     (IN_F * OUT_F / BLK)   // 1,048,576
#define NCODES 65536                   // codebook size
#define M_TOT  8192                    // 4 * 2048
#define K_TOT  IN_F
#define N_TOT  OUT_F
#define NT     (K_TOT / 64)            // 64 K-tiles of BK=64

typedef __bf16 bf16x8 __attribute__((ext_vector_type(8)));
typedef float  f32x4  __attribute__((ext_vector_type(4)));

#define S_BARRIER()  asm volatile("s_barrier" ::: "memory")
#define WAIT_LGKM0() asm volatile("s_waitcnt lgkmcnt(0)" ::: "memory")
#define WAIT_VM(n)   asm volatile("s_waitcnt vmcnt(" #n ")" ::: "memory")

// ---------------------------------------------------------------- convert x
__global__ __launch_bounds__(256) void convert_x_kernel(
    const float* __restrict__ x, __hip_bfloat16* __restrict__ xb) {
  size_t i = ((size_t)blockIdx.x * 256 + threadIdx.x) * 8;
  const float4* p = (const float4*)(x + i);
  float4 a = p[0], b = p[1];
  union { __hip_bfloat16 h[8]; uint4 q; } u;
  u.h[0] = __float2bfloat16(a.x); u.h[1] = __float2bfloat16(a.y);
  u.h[2] = __float2bfloat16(a.z); u.h[3] = __float2bfloat16(a.w);
  u.h[4] = __float2bfloat16(b.x); u.h[5] = __float2bfloat16(b.y);
  u.h[6] = __float2bfloat16(b.z); u.h[7] = __float2bfloat16(b.w);
  *(uint4*)(xb + i) = u.q;
}

// ---------------------------------------------------------------- decode TABLE (MFMA)
// Decode the 65,536 UNIQUE codebook entries once:
// table[k][16] = relu(codebook[k]@W1 + b1)@W2 + b2   (fp32, no scale/shift).
__global__ __launch_bounds__(256) void decode_table_kernel(
    const float* __restrict__ codebook,
    const float* __restrict__ W1, const float* __restrict__ b1,
    const float* __restrict__ W2, const float* __restrict__ b2,
    float* __restrict__ table) {
  __shared__ __align__(16) __hip_bfloat16 sH[4][16 * 72];  // per-wave h tile
  const int lane = threadIdx.x & 63;
  const int wave = threadIdx.x >> 6;
  const int n = lane & 15;   // col within 16
  const int q = lane >> 4;   // quad
  const bool act = q < 2;    // quads holding real K (k<16) for layer 1

  union { __hip_bfloat16 h[8]; bf16x8 v; } uz;
#pragma unroll
  for (int j = 0; j < 8; j++) uz.h[j] = __float2bfloat16(0.f);
  const bf16x8 zf = uz.v;
  const f32x4 z4 = (f32x4){0.f, 0.f, 0.f, 0.f};

  bf16x8 frag1[4];
#pragma unroll
  for (int g = 0; g < 4; g++) {
    union { __hip_bfloat16 h[8]; bf16x8 v; } u;
#pragma unroll
    for (int j = 0; j < 8; j++) {
      int k = (q * 8 + j) & 15;
      float w = act ? W1[k * HID + g * 16 + n] : 0.f;
      u.h[j] = __float2bfloat16(w);
    }
    frag1[g] = u.v;
  }
  bf16x8 frag2[2];
#pragma unroll
  for (int kk = 0; kk < 2; kk++) {
    union { __hip_bfloat16 h[8]; bf16x8 v; } u;
#pragma unroll
    for (int j = 0; j < 8; j++)
      u.h[j] = __float2bfloat16(W2[(kk * 32 + q * 8 + j) * BLK + n]);
    frag2[kk] = u.v;
  }
  float b1v[4];
#pragma unroll
  for (int g = 0; g < 4; g++) b1v[g] = b1[g * 16 + n];
  const float b2v = b2[n];

  const int c0w = blockIdx.x * 256 + wave * 64;
#pragma unroll 1
  for (int i = 0; i < 4; i++) {
    const int cbase = c0w + i * 16;
    const int id = cbase + n;  // sequential: decoding the codebook itself
    const float4* cp = (const float4*)(codebook + (size_t)id * D_LAT + (q & 1) * 8);
    float4 ca = cp[0], cb = cp[1];
    union { __hip_bfloat16 h[8]; bf16x8 v; } ua;
    ua.h[0] = __float2bfloat16(ca.x); ua.h[1] = __float2bfloat16(ca.y);
    ua.h[2] = __float2bfloat16(ca.z); ua.h[3] = __float2bfloat16(ca.w);
    ua.h[4] = __float2bfloat16(cb.x); ua.h[5] = __float2bfloat16(cb.y);
    ua.h[6] = __float2bfloat16(cb.z); ua.h[7] = __float2bfloat16(cb.w);
    bf16x8 afrag = act ? ua.v : zf;

    f32x4 hC[4];
#pragma unroll
    for (int g = 0; g < 4; g++)
      hC[g] = __builtin_amdgcn_mfma_f32_16x16x32_bf16(afrag, frag1[g], z4, 0, 0, 0);

    __syncthreads();
#pragma unroll
    for (int g = 0; g < 4; g++)
#pragma unroll
      for (int r = 0; r < 4; r++) {
        float hv = fmaxf(hC[g][r] + b1v[g], 0.f);
        sH[wave][(q * 4 + r) * 72 + g * 16 + n] = __float2bfloat16(hv);
      }
    __syncthreads();

    bf16x8 a2_0 = *(const bf16x8*)&sH[wave][n * 72 + q * 8];
    bf16x8 a2_1 = *(const bf16x8*)&sH[wave][n * 72 + 32 + q * 8];
    f32x4 o4 = __builtin_amdgcn_mfma_f32_16x16x32_bf16(a2_0, frag2[0], z4, 0, 0, 0);
    o4 = __builtin_amdgcn_mfma_f32_16x16x32_bf16(a2_1, frag2[1], o4, 0, 0, 0);

#pragma unroll
    for (int r = 0; r < 4; r++) {
      int code = cbase + q * 4 + r;
      table[(size_t)code * BLK + n] = o4[r] + b2v;  // fp32, pre-scale
    }
  }
}

// ---------------------------------------------------------------- gather + de-standardize
__global__ __launch_bounds__(256) void gather_scale_kernel(
    const int* __restrict__ yidx, const float* __restrict__ table,
    const float* __restrict__ scale, const float* __restrict__ shift,
    __hip_bfloat16* __restrict__ What) {
  const int b = blockIdx.x * 256 + threadIdx.x;   // weight-block index
  const int o = blockIdx.x;                        // = b >> 8 (256 blocks/row)
  const float sc = scale[o], sh = shift[o];
  const int id = yidx[b];
  const float4* t = (const float4*)(table + (size_t)id * BLK);
  float4 v0 = t[0], v1 = t[1], v2 = t[2], v3 = t[3];
  union { __hip_bfloat16 h[16]; uint4 q[2]; } u;
  u.h[0]  = __float2bfloat16(v0.x * sc + sh);
  u.h[1]  = __float2bfloat16(v0.y * sc + sh);
  u.h[2]  = __float2bfloat16(v0.z * sc + sh);
  u.h[3]  = __float2bfloat16(v0.w * sc + sh);
  u.h[4]  = __float2bfloat16(v1.x * sc + sh);
  u.h[5]  = __float2bfloat16(v1.y * sc + sh);
  u.h[6]  = __float2bfloat16(v1.z * sc + sh);
  u.h[7]  = __float2bfloat16(v1.w * sc + sh);
  u.h[8]  = __float2bfloat16(v2.x * sc + sh);
  u.h[9]  = __float2bfloat16(v2.y * sc + sh);
  u.h[10] = __float2bfloat16(v2.z * sc + sh);
  u.h[11] = __float2bfloat16(v2.w * sc + sh);
  u.h[12] = __float2bfloat16(v3.x * sc + sh);
  u.h[13] = __float2bfloat16(v3.y * sc + sh);
  u.h[14] = __float2bfloat16(v3.z * sc + sh);
  u.h[15] = __float2bfloat16(v3.w * sc + sh);
  uint4* dst = (uint4*)(What + (size_t)b * BLK);
  dst[0] = u.q[0];
  dst[1] = u.q[1];
}

// ---------------------------------------------------------------- GEMM (8-phase 256x256)
// C[m][n] = sum_k A[m][k]*B[n][k] + bias[n].  BM=BN=256, BK=64, 8 waves (2Mx4N),
// 128 KiB LDS double buffer (tile t even->buf0, odd->buf1).
// QUAD->HALF mapping is exact (R2 bugfix): READ_A(.,mh) touches ONLY A-half mh
// (row = mh*128 + wm*64 + mt*16 + fl); READ_B(.,nh) only B-half nh
// (row = nh*128 + wn*32 + nt*16 + fl).  Region liveness per iteration:
//   A-half0 free after P1, B-half0 after P1, B-half1 after P2, A-half1 after P3
// so stages A0@P2, B0@P3, A1@P4 (buf0) and A0@P6, B0@P7, A1@P8 (buf1), B1@P1/P5
// never overwrite live data.  Counted vmcnt(6)=3 half-tiles at P4/P8 only.
// T2 swizzle: linear LDS dest (global_load_lds), inverse-swizzled GLOBAL
// source, swizzled ds_read (colbyte ^= (row&7)<<4).
__device__ inline void gload_lds16(const void* g, void* l) {
  __builtin_amdgcn_global_load_lds(
      (const __attribute__((address_space(1))) void*)g,
      (__attribute__((address_space(3))) void*)l, 16, 0, 0);
}

__global__ __launch_bounds__(512, 2) void gemm_8ph_kernel(
    const __hip_bfloat16* __restrict__ A, const __hip_bfloat16* __restrict__ B,
    const float* __restrict__ bias, float* __restrict__ C) {
  // buf P at P*65536; A half h at +h*16384; B half h at +32768 + h*16384
  __shared__ __align__(16) char ldsb[131072];
  const int tid  = threadIdx.x;
  const int lane = tid & 63;
  const int wave = tid >> 6;
  const int wm = wave >> 2;   // 0..1
  const int wn = wave & 3;    // 0..3
  const int fl = lane & 15;
  const int q  = lane >> 4;

  // XCD-aware swizzle: 512 wgs, 8 XCDs, 64 contiguous wgs per XCD (bijective).
  const int bid = blockIdx.x;
  const int wg  = (bid & 7) * 64 + (bid >> 3);
  const int m0 = (wg >> 4) * 256;   // 32 m-blocks
  const int n0 = (wg & 15) * 256;   // 16 n-blocks

  const __hip_bfloat16* Ab = A + (size_t)m0 * K_TOT;
  const __hip_bfloat16* Bb = B + (size_t)n0 * K_TOT;

  // staging thread geometry: load l covers linear LDS slot tid*16 within the
  // half's 8192*l chunk (rows l*64..l*64+63); global source inverse-swizzled.
  const int r0s = tid >> 3;                 // row 0..63   (l=0)
  const int r1s = r0s + 64;                 // row 64..127 (l=1); (r1s&7)==(r0s&7)
  const int cbs = ((tid & 7) << 4) ^ ((r0s & 7) << 4);  // inverse-swizzled col byte
  const size_t e0 = (size_t)r0s * K_TOT + (cbs >> 1);
  const size_t e1 = (size_t)r1s * K_TOT + (cbs >> 1);

  // read-side lane constants
  const int sw  = (fl & 7) << 4;
  const int cA0 = (q * 16) ^ sw;        // kk=0 col byte (swizzled)
  const int cA1 = (64 + q * 16) ^ sw;   // kk=1
  const int aRow = (wm * 64 + fl) * 128;           // byte base within A half
  const int bRow = 32768 + (wn * 32 + fl) * 128;   // byte base within B half

#define STAGE_A(tt, hh, PP) do {                                               \
    gload_lds16(Ab + (size_t)(hh) * 128 * K_TOT + (size_t)(tt) * 64 + e0,      \
                ldsb + (PP) * 65536 + (hh) * 16384 + wave * 1024);             \
    gload_lds16(Ab + (size_t)(hh) * 128 * K_TOT + (size_t)(tt) * 64 + e1,      \
                ldsb + (PP) * 65536 + (hh) * 16384 + 8192 + wave * 1024);      \
  } while (0)
#define STAGE_B(tt, hh, PP) do {                                               \
    gload_lds16(Bb + (size_t)(hh) * 128 * K_TOT + (size_t)(tt) * 64 + e0,      \
                ldsb + (PP) * 65536 + 32768 + (hh) * 16384 + wave * 1024);     \
    gload_lds16(Bb + (size_t)(hh) * 128 * K_TOT + (size_t)(tt) * 64 + e1,      \
                ldsb + (PP) * 65536 + 32768 + (hh) * 16384 + 8192 + wave * 1024);\
  } while (0)

  bf16x8 aF[4][2], bF0[2][2], bF1[2][2];
  f32x4 acc[8][4];
#pragma unroll
  for (int i = 0; i < 8; i++)
#pragma unroll
    for (int j = 0; j < 4; j++) acc[i][j] = (f32x4){0.f, 0.f, 0.f, 0.f};

#define READ_A(PP, mh) do { _Pragma("unroll")                                  \
    for (int mt = 0; mt < 4; ++mt) {                                           \
      aF[mt][0] = *(const bf16x8*)(ldsb + (PP) * 65536 + (mh) * 16384 +        \
                                   aRow + mt * 2048 + cA0);                    \
      aF[mt][1] = *(const bf16x8*)(ldsb + (PP) * 65536 + (mh) * 16384 +        \
                                   aRow + mt * 2048 + cA1);                    \
    } } while (0)
#define READ_B(PP, nh, DST) do { _Pragma("unroll")                             \
    for (int nt = 0; nt < 2; ++nt) {                                           \
      DST[nt][0] = *(const bf16x8*)(ldsb + (PP) * 65536 + (nh) * 16384 +       \
                                    bRow + nt * 2048 + cA0);                   \
      DST[nt][1] = *(const bf16x8*)(ldsb + (PP) * 65536 + (nh) * 16384 +       \
                                    bRow + nt * 2048 + cA1);                   \
    } } while (0)
#define MFMA16(mh, nh, BF) do {                                                \
    __builtin_amdgcn_s_setprio(1);                                             \
    _Pragma("unroll") for (int mt = 0; mt < 4; ++mt)                           \
    _Pragma("unroll") for (int nt = 0; nt < 2; ++nt) {                         \
      f32x4 c = acc[(mh) * 4 + mt][(nh) * 2 + nt];                             \
      c = __builtin_amdgcn_mfma_f32_16x16x32_bf16(aF[mt][0], BF[nt][0], c, 0, 0, 0); \
      c = __builtin_amdgcn_mfma_f32_16x16x32_bf16(aF[mt][1], BF[nt][1], c, 0, 0, 0); \
      acc[(mh) * 4 + mt][(nh) * 2 + nt] = c;                                   \
    }                                                                          \
    __builtin_amdgcn_s_setprio(0);                                             \
  } while (0)

  // prologue: tile0 (4 halves -> buf0), tile1 A0,A1,B0 -> buf1. vmcnt(6)
  // leaves exactly the 3 tile-1 halves (6 loads) in flight; tile0 landed.
  STAGE_A(0, 0, 0); STAGE_A(0, 1, 0); STAGE_B(0, 0, 0); STAGE_B(0, 1, 0);
  STAGE_A(1, 0, 1); STAGE_A(1, 1, 1); STAGE_B(1, 0, 1);
  WAIT_VM(6);
  S_BARRIER();

#pragma unroll 1
  for (int t = 0; t < NT; t += 2) {
    const bool s2 = (t + 2) < NT;
    const bool s3 = (t + 3) < NT;
    // ---- phase 1: A-half0 x B-half0 of tile t (buf0); stage B1(t+1)->buf1
    READ_A(0, 0); READ_B(0, 0, bF0);
    STAGE_B(t + 1, 1, 1);
    S_BARRIER(); WAIT_LGKM0();
    MFMA16(0, 0, bF0);
    S_BARRIER();
    // ---- phase 2: A-half0 x B-half1; stage A0(t+2)->buf0 (A-half0 freed @P1)
    READ_B(0, 1, bF1);
    if (s2) STAGE_A(t + 2, 0, 0);
    S_BARRIER(); WAIT_LGKM0();
    MFMA16(0, 1, bF1);
    S_BARRIER();
    // ---- phase 3: A-half1 x B-half1; stage B0(t+2)->buf0 (B-half0 freed @P1)
    READ_A(0, 1);
    if (s2) STAGE_B(t + 2, 0, 0);
    S_BARRIER(); WAIT_LGKM0();
    MFMA16(1, 1, bF1);
    S_BARRIER();
    // ---- phase 4: A-half1 x B-half0; stage A1(t+2)->buf0 (A-half1 freed @P3)
    if (s2) { STAGE_A(t + 2, 1, 0); WAIT_VM(6); } else { WAIT_VM(0); }
    S_BARRIER();
    MFMA16(1, 0, bF0);
    S_BARRIER();
    // ---- phase 5: tile t+1 (buf1): A-half0 x B-half0; stage B1(t+2)->buf0
    READ_A(1, 0); READ_B(1, 0, bF0);
    if (s2) STAGE_B(t + 2, 1, 0);
    S_BARRIER(); WAIT_LGKM0();
    MFMA16(0, 0, bF0);
    S_BARRIER();
    // ---- phase 6: A-half0 x B-half1; stage A0(t+3)->buf1 (A-half0 freed @P5)
    READ_B(1, 1, bF1);
    if (s3) STAGE_A(t + 3, 0, 1);
    S_BARRIER(); WAIT_LGKM0();
    MFMA16(0, 1, bF1);
    S_BARRIER();
    // ---- phase 7: A-half1 x B-half1; stage B0(t+3)->buf1 (B-half0 freed @P5)
    READ_A(1, 1);
    if (s3) STAGE_B(t + 3, 0, 1);
    S_BARRIER(); WAIT_LGKM0();
    MFMA16(1, 1, bF1);
    S_BARRIER();
    // ---- phase 8: A-half1 x B-half0; stage A1(t+3)->buf1 (A-half1 freed @P7)
    if (s3) { STAGE_A(t + 3, 1, 1); WAIT_VM(6); } else { WAIT_VM(0); }
    S_BARRIER();
    MFMA16(1, 0, bF0);
    S_BARRIER();
  }

  // ---- epilogue: bias + store (fp32).  acc[mt][nt] -> C row/col per the
  // quad->half mapping: row = (mt>>2)*128 + wm*64 + (mt&3)*16 + q*4 + r,
  //                     col = (nt>>1)*128 + wn*32 + (nt&1)*16 + fl.
  float bs[4];
#pragma unroll
  for (int nt = 0; nt < 4; nt++)
    bs[nt] = bias[n0 + (nt >> 1) * 128 + wn * 32 + (nt & 1) * 16 + fl];
#pragma unroll
  for (int mt = 0; mt < 8; mt++) {
    int r0 = m0 + (mt >> 2) * 128 + wm * 64 + (mt & 3) * 16 + q * 4;
#pragma unroll
    for (int nt = 0; nt < 4; nt++) {
      int cn = n0 + (nt >> 1) * 128 + wn * 32 + (nt & 1) * 16 + fl;
#pragma unroll
      for (int r = 0; r < 4; r++)
        C[(size_t)(r0 + r) * N_TOT + cn] = acc[mt][nt][r] + bs[nt];
    }
  }
#undef STAGE_A
#undef STAGE_B
#undef READ_A
#undef READ_B
#undef MFMA16
}

// ---------------------------------------------------------------- launch
extern "C" void kernel_launch(void* const* d_in, const int* in_sizes, int n_in,
                              void* d_out, int out_size, void* d_ws, size_t ws_size,
                              hipStream_t stream) {
  const float* x        = (const float*)d_in[0];
  const int*   yidx     = (const int*)d_in[1];
  const float* codebook = (const float*)d_in[2];
  const float* W1       = (const float*)d_in[3];
  const float* b1       = (const float*)d_in[4];
  const float* W2       = (const float*)d_in[5];
  const float* b2       = (const float*)d_in[6];
  const float* scale    = (const float*)d_in[7];
  const float* shift    = (const float*)d_in[8];
  const float* bias     = (const float*)d_in[9];
  float* out = (float*)d_out;

  // Workspace layout (96 MB):
  //   [0,32MB)  What  (bf16)
  //   [32,96MB) xb    (bf16 x) -- first 4 MB double as fp32 decode table,
  //                               dead before convert_x runs (stream-ordered).
  __hip_bfloat16* What = (__hip_bfloat16*)d_ws;                                     // 32 MB
  float* table = (float*)((char*)d_ws + (size_t)32 * 1024 * 1024);                  //  4 MB (aliased)
  __hip_bfloat16* xb   = (__hip_bfloat16*)((char*)d_ws + (size_t)32 * 1024 * 1024); // 64 MB

  decode_table_kernel<<<NCODES / 256, 256, 0, stream>>>(codebook, W1, b1, W2, b2,
                                                        table);
  gather_scale_kernel<<<NB / 256, 256, 0, stream>>>(yidx, table, scale, shift, What);
  convert_x_kernel<<<(M_TOT * (size_t)K_TOT) / (256 * 8), 256, 0, stream>>>(x, xb);
  gemm_8ph_kernel<<<512, 512, 0, stream>>>(xb, What, bias, out);
}

// Round 5
// 474.772 us; speedup vs baseline: 1.1565x; 1.0202x over previous
//
#include <hip/hip_runtime.h>
#include <hip/hip_bf16.h>

#define IN_F   4096
#define OUT_F  4096
#define HID    64
#define D_LAT  16
#define BLK    16
#define NB     (IN_F * OUT_F / BLK)   // 1,048,576
#define NCODES 65536                   // codebook size
#define M_TOT  8192                    // 4 * 2048
#define K_TOT  IN_F
#define N_TOT  OUT_F
#define NT     (K_TOT / 64)            // 64 K-tiles of BK=64

typedef __bf16 bf16x8 __attribute__((ext_vector_type(8)));
typedef float  f32x4  __attribute__((ext_vector_type(4)));

#define S_BARRIER()  asm volatile("s_barrier" ::: "memory")
#define WAIT_VM(n)   asm volatile("s_waitcnt vmcnt(" #n ")" ::: "memory")

// ---------------------------------------------------------------- convert x
__global__ __launch_bounds__(256) void convert_x_kernel(
    const float* __restrict__ x, __hip_bfloat16* __restrict__ xb) {
  size_t i = ((size_t)blockIdx.x * 256 + threadIdx.x) * 8;
  const float4* p = (const float4*)(x + i);
  float4 a = p[0], b = p[1];
  union { __hip_bfloat16 h[8]; uint4 q; } u;
  u.h[0] = __float2bfloat16(a.x); u.h[1] = __float2bfloat16(a.y);
  u.h[2] = __float2bfloat16(a.z); u.h[3] = __float2bfloat16(a.w);
  u.h[4] = __float2bfloat16(b.x); u.h[5] = __float2bfloat16(b.y);
  u.h[6] = __float2bfloat16(b.z); u.h[7] = __float2bfloat16(b.w);
  *(uint4*)(xb + i) = u.q;
}

// ---------------------------------------------------------------- decode TABLE (MFMA)
// Decode the 65,536 UNIQUE codebook entries once:
// table[k][16] = relu(codebook[k]@W1 + b1)@W2 + b2   (fp32, no scale/shift).
__global__ __launch_bounds__(256) void decode_table_kernel(
    const float* __restrict__ codebook,
    const float* __restrict__ W1, const float* __restrict__ b1,
    const float* __restrict__ W2, const float* __restrict__ b2,
    float* __restrict__ table) {
  __shared__ __align__(16) __hip_bfloat16 sH[4][16 * 72];  // per-wave h tile
  const int lane = threadIdx.x & 63;
  const int wave = threadIdx.x >> 6;
  const int n = lane & 15;   // col within 16
  const int q = lane >> 4;   // quad
  const bool act = q < 2;    // quads holding real K (k<16) for layer 1

  union { __hip_bfloat16 h[8]; bf16x8 v; } uz;
#pragma unroll
  for (int j = 0; j < 8; j++) uz.h[j] = __float2bfloat16(0.f);
  const bf16x8 zf = uz.v;
  const f32x4 z4 = (f32x4){0.f, 0.f, 0.f, 0.f};

  bf16x8 frag1[4];
#pragma unroll
  for (int g = 0; g < 4; g++) {
    union { __hip_bfloat16 h[8]; bf16x8 v; } u;
#pragma unroll
    for (int j = 0; j < 8; j++) {
      int k = (q * 8 + j) & 15;
      float w = act ? W1[k * HID + g * 16 + n] : 0.f;
      u.h[j] = __float2bfloat16(w);
    }
    frag1[g] = u.v;
  }
  bf16x8 frag2[2];
#pragma unroll
  for (int kk = 0; kk < 2; kk++) {
    union { __hip_bfloat16 h[8]; bf16x8 v; } u;
#pragma unroll
    for (int j = 0; j < 8; j++)
      u.h[j] = __float2bfloat16(W2[(kk * 32 + q * 8 + j) * BLK + n]);
    frag2[kk] = u.v;
  }
  float b1v[4];
#pragma unroll
  for (int g = 0; g < 4; g++) b1v[g] = b1[g * 16 + n];
  const float b2v = b2[n];

  const int c0w = blockIdx.x * 256 + wave * 64;
#pragma unroll 1
  for (int i = 0; i < 4; i++) {
    const int cbase = c0w + i * 16;
    const int id = cbase + n;  // sequential: decoding the codebook itself
    const float4* cp = (const float4*)(codebook + (size_t)id * D_LAT + (q & 1) * 8);
    float4 ca = cp[0], cb = cp[1];
    union { __hip_bfloat16 h[8]; bf16x8 v; } ua;
    ua.h[0] = __float2bfloat16(ca.x); ua.h[1] = __float2bfloat16(ca.y);
    ua.h[2] = __float2bfloat16(ca.z); ua.h[3] = __float2bfloat16(ca.w);
    ua.h[4] = __float2bfloat16(cb.x); ua.h[5] = __float2bfloat16(cb.y);
    ua.h[6] = __float2bfloat16(cb.z); ua.h[7] = __float2bfloat16(cb.w);
    bf16x8 afrag = act ? ua.v : zf;

    f32x4 hC[4];
#pragma unroll
    for (int g = 0; g < 4; g++)
      hC[g] = __builtin_amdgcn_mfma_f32_16x16x32_bf16(afrag, frag1[g], z4, 0, 0, 0);

    __syncthreads();
#pragma unroll
    for (int g = 0; g < 4; g++)
#pragma unroll
      for (int r = 0; r < 4; r++) {
        float hv = fmaxf(hC[g][r] + b1v[g], 0.f);
        sH[wave][(q * 4 + r) * 72 + g * 16 + n] = __float2bfloat16(hv);
      }
    __syncthreads();

    bf16x8 a2_0 = *(const bf16x8*)&sH[wave][n * 72 + q * 8];
    bf16x8 a2_1 = *(const bf16x8*)&sH[wave][n * 72 + 32 + q * 8];
    f32x4 o4 = __builtin_amdgcn_mfma_f32_16x16x32_bf16(a2_0, frag2[0], z4, 0, 0, 0);
    o4 = __builtin_amdgcn_mfma_f32_16x16x32_bf16(a2_1, frag2[1], o4, 0, 0, 0);

#pragma unroll
    for (int r = 0; r < 4; r++) {
      int code = cbase + q * 4 + r;
      table[(size_t)code * BLK + n] = o4[r] + b2v;  // fp32, pre-scale
    }
  }
}

// ---------------------------------------------------------------- gather + de-standardize
__global__ __launch_bounds__(256) void gather_scale_kernel(
    const int* __restrict__ yidx, const float* __restrict__ table,
    const float* __restrict__ scale, const float* __restrict__ shift,
    __hip_bfloat16* __restrict__ What) {
  const int b = blockIdx.x * 256 + threadIdx.x;   // weight-block index
  const int o = blockIdx.x;                        // = b >> 8 (256 blocks/row)
  const float sc = scale[o], sh = shift[o];
  const int id = yidx[b];
  const float4* t = (const float4*)(table + (size_t)id * BLK);
  float4 v0 = t[0], v1 = t[1], v2 = t[2], v3 = t[3];
  union { __hip_bfloat16 h[16]; uint4 q[2]; } u;
  u.h[0]  = __float2bfloat16(v0.x * sc + sh);
  u.h[1]  = __float2bfloat16(v0.y * sc + sh);
  u.h[2]  = __float2bfloat16(v0.z * sc + sh);
  u.h[3]  = __float2bfloat16(v0.w * sc + sh);
  u.h[4]  = __float2bfloat16(v1.x * sc + sh);
  u.h[5]  = __float2bfloat16(v1.y * sc + sh);
  u.h[6]  = __float2bfloat16(v1.z * sc + sh);
  u.h[7]  = __float2bfloat16(v1.w * sc + sh);
  u.h[8]  = __float2bfloat16(v2.x * sc + sh);
  u.h[9]  = __float2bfloat16(v2.y * sc + sh);
  u.h[10] = __float2bfloat16(v2.z * sc + sh);
  u.h[11] = __float2bfloat16(v2.w * sc + sh);
  u.h[12] = __float2bfloat16(v3.x * sc + sh);
  u.h[13] = __float2bfloat16(v3.y * sc + sh);
  u.h[14] = __float2bfloat16(v3.z * sc + sh);
  u.h[15] = __float2bfloat16(v3.w * sc + sh);
  uint4* dst = (uint4*)(What + (size_t)b * BLK);
  dst[0] = u.q[0];
  dst[1] = u.q[1];
}

// ---------------------------------------------------------------- GEMM (1-barrier 8-phase)
// C[m][n] = sum_k A[m][k]*B[n][k] + bias[n].  BM=BN=256, BK=64, 8 waves (2Mx4N),
// 128 KiB LDS double buffer.  ONE barrier per phase; each phase:
//   [BAR; STAGE half-tile; MFMA (frags read LAST phase); tail-READS next frags]
// Fragment banks alternate (aF shared A0/A1, bF0, bF1) so one-phase-ahead
// reads need ZERO extra registers.  Liveness ledger (per iteration):
//   stage@P2->bufA0 : A0 reads at tailP8(prev), consumed MFMA@P1  (< BAR P2)
//   stage@P3->bufB0 : B0 reads at tailP8(prev), consumed MFMA@P1  (< BAR P3)
//   stage@P4->bufA1 : A1 reads at tailP2, consumed MFMA@P3        (< BAR P4)
//   stage@P5->bufB1 : B1 reads at tailP1, consumed MFMA@P2/P3     (< BAR P5)
//   P6/P7/P8/P1 mirrored on buf1.
// vmcnt(4) at end-P3 drains tile-(t+1)'s 8 loads; barrier P4 extends the
// per-wave guarantee to all waves before the tail-P4 reads of buf1.
// vmcnt(4) at end-P7 same for tile t+2 / tail-P8 reads of buf0.
__device__ inline void gload_lds16(const void* g, void* l) {
  __builtin_amdgcn_global_load_lds(
      (const __attribute__((address_space(1))) void*)g,
      (__attribute__((address_space(3))) void*)l, 16, 0, 0);
}

__global__ __launch_bounds__(512, 2) void gemm_1bar_kernel(
    const __hip_bfloat16* __restrict__ A, const __hip_bfloat16* __restrict__ B,
    const float* __restrict__ bias, float* __restrict__ C) {
  // buf P at P*65536; A half h at +h*16384; B half h at +32768 + h*16384
  __shared__ __align__(16) char ldsb[131072];
  const int tid  = threadIdx.x;
  const int lane = tid & 63;
  const int wave = tid >> 6;
  const int wm = wave >> 2;   // 0..1
  const int wn = wave & 3;    // 0..3
  const int fl = lane & 15;
  const int q  = lane >> 4;

  // XCD-aware swizzle: 512 wgs, 8 XCDs, 64 contiguous wgs per XCD (bijective).
  const int bid = blockIdx.x;
  const int wg  = (bid & 7) * 64 + (bid >> 3);
  const int m0 = (wg >> 4) * 256;   // 32 m-blocks
  const int n0 = (wg & 15) * 256;   // 16 n-blocks

  const __hip_bfloat16* Ab = A + (size_t)m0 * K_TOT;
  const __hip_bfloat16* Bb = B + (size_t)n0 * K_TOT;

  // staging thread geometry: load l covers rows l*64..l*64+63 of the half;
  // global source inverse-swizzled so linear LDS dest + swizzled read match.
  const int r0s = tid >> 3;                 // row 0..63   (l=0)
  const int r1s = r0s + 64;                 // row 64..127 (l=1); (r1s&7)==(r0s&7)
  const int cbs = ((tid & 7) << 4) ^ ((r0s & 7) << 4);  // inverse-swizzled col byte
  const size_t e0 = (size_t)r0s * K_TOT + (cbs >> 1);
  const size_t e1 = (size_t)r1s * K_TOT + (cbs >> 1);

  // read-side lane constants
  const int sw  = (fl & 7) << 4;
  const int cA0 = (q * 16) ^ sw;        // kk=0 col byte (swizzled)
  const int cA1 = (64 + q * 16) ^ sw;   // kk=1
  const int aRow = (wm * 64 + fl) * 128;           // byte base within A half
  const int bRow = 32768 + (wn * 32 + fl) * 128;   // byte base within B half

#define STAGE_A(tt, hh, PP) do {                                               \
    gload_lds16(Ab + (size_t)(hh) * 128 * K_TOT + (size_t)(tt) * 64 + e0,      \
                ldsb + (PP) * 65536 + (hh) * 16384 + wave * 1024);             \
    gload_lds16(Ab + (size_t)(hh) * 128 * K_TOT + (size_t)(tt) * 64 + e1,      \
                ldsb + (PP) * 65536 + (hh) * 16384 + 8192 + wave * 1024);      \
  } while (0)
#define STAGE_B(tt, hh, PP) do {                                               \
    gload_lds16(Bb + (size_t)(hh) * 128 * K_TOT + (size_t)(tt) * 64 + e0,      \
                ldsb + (PP) * 65536 + 32768 + (hh) * 16384 + wave * 1024);     \
    gload_lds16(Bb + (size_t)(hh) * 128 * K_TOT + (size_t)(tt) * 64 + e1,      \
                ldsb + (PP) * 65536 + 32768 + (hh) * 16384 + 8192 + wave * 1024);\
  } while (0)

  bf16x8 aF[4][2], bF0[2][2], bF1[2][2];
  f32x4 acc[8][4];
#pragma unroll
  for (int i = 0; i < 8; i++)
#pragma unroll
    for (int j = 0; j < 4; j++) acc[i][j] = (f32x4){0.f, 0.f, 0.f, 0.f};

#define READ_A(PP, mh) do { _Pragma("unroll")                                  \
    for (int mt = 0; mt < 4; ++mt) {                                           \
      aF[mt][0] = *(const bf16x8*)(ldsb + (PP) * 65536 + (mh) * 16384 +        \
                                   aRow + mt * 2048 + cA0);                    \
      aF[mt][1] = *(const bf16x8*)(ldsb + (PP) * 65536 + (mh) * 16384 +        \
                                   aRow + mt * 2048 + cA1);                    \
    } } while (0)
#define READ_B(PP, nh, DST) do { _Pragma("unroll")                             \
    for (int nt = 0; nt < 2; ++nt) {                                           \
      DST[nt][0] = *(const bf16x8*)(ldsb + (PP) * 65536 + (nh) * 16384 +       \
                                    bRow + nt * 2048 + cA0);                   \
      DST[nt][1] = *(const bf16x8*)(ldsb + (PP) * 65536 + (nh) * 16384 +       \
                                    bRow + nt * 2048 + cA1);                   \
    } } while (0)
#define MFMA16(mh, nh, BF) do {                                                \
    __builtin_amdgcn_s_setprio(1);                                             \
    _Pragma("unroll") for (int mt = 0; mt < 4; ++mt)                           \
    _Pragma("unroll") for (int nt = 0; nt < 2; ++nt) {                         \
      f32x4 c = acc[(mh) * 4 + mt][(nh) * 2 + nt];                             \
      c = __builtin_amdgcn_mfma_f32_16x16x32_bf16(aF[mt][0], BF[nt][0], c, 0, 0, 0); \
      c = __builtin_amdgcn_mfma_f32_16x16x32_bf16(aF[mt][1], BF[nt][1], c, 0, 0, 0); \
      acc[(mh) * 4 + mt][(nh) * 2 + nt] = c;                                   \
    }                                                                          \
    __builtin_amdgcn_s_setprio(0);                                             \
  } while (0)

  // prologue: tile0 (4 halves -> buf0: 8 loads), tile1 A0,A1,B0 -> buf1 (6).
  // vmcnt(6) drains tile0; barrier; pre-read A0,B0 of tile0 for P1's MFMA.
  STAGE_A(0, 0, 0); STAGE_A(0, 1, 0); STAGE_B(0, 0, 0); STAGE_B(0, 1, 0);
  STAGE_A(1, 0, 1); STAGE_A(1, 1, 1); STAGE_B(1, 0, 1);
  WAIT_VM(6);
  S_BARRIER();
  READ_A(0, 0); READ_B(0, 0, bF0);

#pragma unroll 1
  for (int t = 0; t < NT; t += 2) {
    const bool s2 = (t + 2) < NT;
    const bool s3 = (t + 3) < NT;
    // ---- P1: MFMA A0xB0 (tile t); stage B1(t+1)->buf1; tail-read B1(t)
    S_BARRIER();
    STAGE_B(t + 1, 1, 1);
    MFMA16(0, 0, bF0);
    READ_B(0, 1, bF1);
    // ---- P2: MFMA A0xB1; stage A0(t+2)->buf0; tail-read A1(t)
    S_BARRIER();
    if (s2) STAGE_A(t + 2, 0, 0);
    MFMA16(0, 1, bF1);
    READ_A(0, 1);
    // ---- P3: MFMA A1xB1; stage B0(t+2)->buf0; drain tile-(t+1) DMA
    S_BARRIER();
    if (s2) STAGE_B(t + 2, 0, 0);
    MFMA16(1, 1, bF1);
    if (s2) { WAIT_VM(4); } else { WAIT_VM(0); }
    // ---- P4: MFMA A1xB0; stage A1(t+2)->buf0; tail-read A0,B0 (t+1, buf1)
    S_BARRIER();
    if (s2) STAGE_A(t + 2, 1, 0);
    MFMA16(1, 0, bF0);
    READ_A(1, 0); READ_B(1, 0, bF0);
    // ---- P5: MFMA A0xB0 (tile t+1); stage B1(t+2)->buf0; tail-read B1(t+1)
    S_BARRIER();
    if (s2) STAGE_B(t + 2, 1, 0);
    MFMA16(0, 0, bF0);
    READ_B(1, 1, bF1);
    // ---- P6: MFMA A0xB1; stage A0(t+3)->buf1; tail-read A1(t+1)
    S_BARRIER();
    if (s3) STAGE_A(t + 3, 0, 1);
    MFMA16(0, 1, bF1);
    READ_A(1, 1);
    // ---- P7: MFMA A1xB1; stage B0(t+3)->buf1; drain tile-(t+2) DMA
    S_BARRIER();
    if (s3) STAGE_B(t + 3, 0, 1);
    MFMA16(1, 1, bF1);
    if (s3) { WAIT_VM(4); } else { WAIT_VM(0); }
    // ---- P8: MFMA A1xB0; stage A1(t+3)->buf1; tail-read A0,B0 (t+2, buf0)
    S_BARRIER();
    if (s3) STAGE_A(t + 3, 1, 1);
    MFMA16(1, 0, bF0);
    if (s2) { READ_A(0, 0); READ_B(0, 0, bF0); }
  }

  // ---- epilogue: bias + store (fp32).  acc[mt][nt] -> C per quad->half map:
  // row = (mt>>2)*128 + wm*64 + (mt&3)*16 + q*4 + r,
  // col = (nt>>1)*128 + wn*32 + (nt&1)*16 + fl.
  float bs[4];
#pragma unroll
  for (int nt = 0; nt < 4; nt++)
    bs[nt] = bias[n0 + (nt >> 1) * 128 + wn * 32 + (nt & 1) * 16 + fl];
#pragma unroll
  for (int mt = 0; mt < 8; mt++) {
    int r0 = m0 + (mt >> 2) * 128 + wm * 64 + (mt & 3) * 16 + q * 4;
#pragma unroll
    for (int nt = 0; nt < 4; nt++) {
      int cn = n0 + (nt >> 1) * 128 + wn * 32 + (nt & 1) * 16 + fl;
#pragma unroll
      for (int r = 0; r < 4; r++)
        C[(size_t)(r0 + r) * N_TOT + cn] = acc[mt][nt][r] + bs[nt];
    }
  }
#undef STAGE_A
#undef STAGE_B
#undef READ_A
#undef READ_B
#undef MFMA16
}

// ---------------------------------------------------------------- launch
extern "C" void kernel_launch(void* const* d_in, const int* in_sizes, int n_in,
                              void* d_out, int out_size, void* d_ws, size_t ws_size,
                              hipStream_t stream) {
  const float* x        = (const float*)d_in[0];
  const int*   yidx     = (const int*)d_in[1];
  const float* codebook = (const float*)d_in[2];
  const float* W1       = (const float*)d_in[3];
  const float* b1       = (const float*)d_in[4];
  const float* W2       = (const float*)d_in[5];
  const float* b2       = (const float*)d_in[6];
  const float* scale    = (const float*)d_in[7];
  const float* shift    = (const float*)d_in[8];
  const float* bias     = (const float*)d_in[9];
  float* out = (float*)d_out;

  // Workspace layout (96 MB) -- R3-verified structure:
  //   [0,32MB)  What  (bf16)
  //   [32,96MB) xb    (bf16 x) -- first 4 MB double as fp32 decode table,
  //                               dead before convert_x runs (stream-ordered:
  //                               decode -> gather -> convert -> gemm).
  __hip_bfloat16* What = (__hip_bfloat16*)d_ws;                                     // 32 MB
  float* table = (float*)((char*)d_ws + (size_t)32 * 1024 * 1024);                  //  4 MB (aliased)
  __hip_bfloat16* xb   = (__hip_bfloat16*)((char*)d_ws + (size_t)32 * 1024 * 1024); // 64 MB

  decode_table_kernel<<<NCODES / 256, 256, 0, stream>>>(codebook, W1, b1, W2, b2,
                                                        table);
  gather_scale_kernel<<<NB / 256, 256, 0, stream>>>(yidx, table, scale, shift, What);
  convert_x_kernel<<<(M_TOT * (size_t)K_TOT) / (256 * 8), 256, 0, stream>>>(x, xb);
  gemm_1bar_kernel<<<512, 512, 0, stream>>>(xb, What, bias, out);
}